// Round 9
// baseline (779.570 us; speedup 1.0000x reference)
//
#include <hip/hip_runtime.h>
#include <cfloat>

typedef _Float16 half8 __attribute__((ext_vector_type(8)));
typedef float    f32x4 __attribute__((ext_vector_type(4)));

#define N_ROWS 65536
#define DIM    256
#define KCODES 4096
#define BM 128
#define BN 128
#define BK 32
#define NSLICE (DIM / BK)      // 8
#define NCHUNK (KCODES / BN)   // 32
#define NITER  (NCHUNK * NSLICE)

// d_ws layout (bytes): csq[4096]f32 | xsq[65536]f32 | ch[1M]f16 | cl[1M]f16
#define WS_CSQ 0
#define WS_XSQ 16384
#define WS_CH  278528
#define WS_CL  2375680

// async global->LDS, 16B per lane, LDS dst = uniform base + lane*16
#define GLDS(g, l) __builtin_amdgcn_global_load_lds(                       \
    (const __attribute__((address_space(1))) unsigned int*)(g),            \
    (__attribute__((address_space(3))) unsigned int*)(l), 16, 0, 0)

// ---- Prologue: csq (k-ascending fmaf chain, matches ref) + cb -> f16 hi/lo planes (x64) ----
__global__ void prep_codes(const float* __restrict__ cb, float* __restrict__ csq,
                           _Float16* __restrict__ ch, _Float16* __restrict__ cl) {
    __shared__ float As[32 * DIM];   // 32KB
    const int t = threadIdx.x;
    const int c0 = blockIdx.x * 32;
    #pragma unroll
    for (int i = 0; i < 8; ++i) {
        int r = 4 * i + (t >> 6), d4 = (t & 63) * 4;
        *(float4*)&As[r * DIM + d4] = *(const float4*)&cb[(size_t)(c0 + r) * DIM + d4];
    }
    __syncthreads();
    {
        const int r = t >> 3;
        const int k0 = (t & 7) * 32;
        const float* src = &As[r * DIM + k0];
        _Float16* dh = &ch[(size_t)(c0 + r) * DIM + k0];
        _Float16* dl = &cl[(size_t)(c0 + r) * DIM + k0];
        #pragma unroll
        for (int i = 0; i < 4; ++i) {
            half8 hv, lv;
            #pragma unroll
            for (int j = 0; j < 8; ++j) {
                float sv = src[i * 8 + j] * 64.f;
                _Float16 h = (_Float16)sv;
                hv[j] = h; lv[j] = (_Float16)(sv - (float)h);
            }
            *(half8*)(dh + i * 8) = hv;
            *(half8*)(dl + i * 8) = lv;
        }
    }
    if (t < 32) {
        const float* row = &As[t * DIM];
        float s = 0.f;
        for (int k = 0; k < DIM; ++k) s = fmaf(row[k], row[k], s);   // k-ascending chain
        csq[c0 + t] = s;
    }
}

// ---- Main: fused x-prep + 3-split f16 MFMA GEMM + fused argmin ----
// Occupancy build: 48KB LDS (A double-buffered 32KB, B single-buffered 16KB) +
// launch_bounds(256,3) -> 3 blocks/CU (12 waves). Per slice:
//   [staggered frag reads + 3 sweeps] [lgkm0+bar] [BSTAGE(j+1), ASTAGE(j+2)]
//   [vmcnt(4): retires A(j+1)+B(j+1), keeps A(j+2) in flight] [bar]
// B is L2-hot (ch/cl shared 2MB) so its short stage exposure is covered by the
// other 2 resident blocks; A keeps a 2-slice pipeline (L3-resident scratch).
__global__ __launch_bounds__(256, 3)
void vq_mfma(const float* __restrict__ x, const float* __restrict__ cb,
             const float* __restrict__ csq,
             const _Float16* __restrict__ ch, const _Float16* __restrict__ cl,
             float* __restrict__ xsqg, float* out_q, float* __restrict__ out_idx) {
    __shared__ __align__(1024) char SMEM[49152];
    _Float16* AhS = (_Float16*)SMEM;                 // 16KB [2][128][32]
    _Float16* AlS = (_Float16*)(SMEM + 16384);       // 16KB
    _Float16* BhS = (_Float16*)(SMEM + 32768);       // 8KB  [128][32]
    _Float16* BlS = (_Float16*)(SMEM + 40960);       // 8KB

    const int t = threadIdx.x;
    const int lane = t & 63, wave = t >> 6;
    const int wy = wave >> 1, wx = wave & 1;
    const int m = lane & 15, q = lane >> 4;   // MFMA: A/B row = m, k-granule = q; C: row=4q+e, col=m
    const int n0 = blockIdx.x * BM;
    const int swz = (q ^ ((m + (m >> 2)) & 3)) * 8;   // frag-read granule offset (f16 units)

    // ======== fused x-prep: 4 groups of 32 rows (verified r3-r7; xsq -> global) ========
    {
        float*  prepF = (float*)SMEM;                  // 32KB
        double* dtmp  = (double*)(SMEM + 32768);       // 1KB
        char*   xqw   = (char*)out_q;
        for (int g = 0; g < 4; ++g) {
            const int r0 = g * 32;
            #pragma unroll
            for (int i = 0; i < 8; ++i) {
                int r = 4 * i + (t >> 6), d4 = (t & 63) * 4;
                *(float4*)&prepF[r * DIM + d4] =
                    *(const float4*)&x[(size_t)(n0 + r0 + r) * DIM + d4];
            }
            __syncthreads();
            {
                const int r = t >> 3;
                const int col8 = (t & 7) * 8;
                char* dst = xqw + (((size_t)(n0 + r0 + r)) << 10) + (size_t)(col8 * 2);
                const float* src = &prepF[r * DIM + col8];
                #pragma unroll
                for (int i = 0; i < 4; ++i) {
                    half8 hv, lv;
                    #pragma unroll
                    for (int j = 0; j < 8; ++j) {
                        float v = src[i * 64 + j];
                        _Float16 h = (_Float16)v;
                        hv[j] = h; lv[j] = (_Float16)(v - (float)h);
                    }
                    *(half8*)(dst + i * 128) = hv;          // hi plane
                    *(half8*)(dst + 512 + i * 128) = lv;    // lo plane
                }
            }
            if (t < 128) {
                int r = t >> 2, part = t & 3;
                const float* ap = &prepF[r * DIM + 64 * part];
                double s = 0.0;
                for (int k = 0; k < 64; ++k) { double v = (double)ap[k]; s = fma(v, v, s); }
                dtmp[t] = s;
            }
            __syncthreads();
            if (t < 32)
                xsqg[n0 + r0 + t] = (float)((dtmp[4*t] + dtmp[4*t+1]) + (dtmp[4*t+2] + dtmp[4*t+3]));
            __syncthreads();
        }
    }
    // plane + xsq stores must be visible before glds / epilogue reads
    asm volatile("s_waitcnt vmcnt(0)" ::: "memory");
    __syncthreads();

    // ======== staging addressing (granule pre-swizzle, verified) ========
    const int rq  = lane >> 2;
    const int gph = lane & 3;
    const int glog = ((gph ^ ((rq + (rq >> 2)) & 3)) << 4);   // source granule, bytes
    const char* aBase  = (const char*)out_q + (((size_t)(n0 + wave * 32 + rq)) << 10) + glog;
    const char* bBaseH = (const char*)ch + (((size_t)(wave * 32 + rq)) << 9) + glog;
    const char* bBaseL = (const char*)cl + (((size_t)(wave * 32 + rq)) << 9) + glog;

    // A slice s -> buf nb (rows wave*32+rq, +16)
#define ASTAGE(s, nb) do {                                                   \
    const char* a_ = aBase + (size_t)((s) * 64);                             \
    _Float16* Ah_ = AhS + (nb) * 4096 + wave * 1024;                         \
    _Float16* Al_ = AlS + (nb) * 4096 + wave * 1024;                         \
    GLDS(a_,           Ah_);                                                 \
    GLDS(a_ + 16384,   Ah_ + 512);                                           \
    GLDS(a_ + 512,     Al_);                                                 \
    GLDS(a_ + 16896,   Al_ + 512);                                           \
} while (0)

    // B (chunk ck, slice s) -> single buffer
#define BSTAGE(ck, s) do {                                                   \
    const size_t bo_ = ((size_t)(ck) << 16) + (size_t)((s) * 64);            \
    const char* bh_ = bBaseH + bo_;                                          \
    const char* bl_ = bBaseL + bo_;                                          \
    _Float16* Bh_ = BhS + wave * 1024;                                       \
    _Float16* Bl_ = BlS + wave * 1024;                                       \
    GLDS(bh_,          Bh_);                                                 \
    GLDS(bh_ + 8192,   Bh_ + 512);                                           \
    GLDS(bl_,          Bl_);                                                 \
    GLDS(bl_ + 8192,   Bl_ + 512);                                           \
} while (0)

#define SWEEP(AF, BF)                                                        \
    _Pragma("unroll")                                                        \
    for (int tc = 0; tc < 4; ++tc)                                           \
        _Pragma("unroll")                                                    \
        for (int tr = 0; tr < 4; ++tr)                                       \
            acc[tr][tc] = __builtin_amdgcn_mfma_f32_16x16x32_f16(AF[tr], BF[tc], acc[tr][tc], 0, 0, 0)

    int aoffs[4], boffs[4];
    #pragma unroll
    for (int tr = 0; tr < 4; ++tr) aoffs[tr] = (64 * wy + 16 * tr + m) * BK + swz;
    #pragma unroll
    for (int tc = 0; tc < 4; ++tc) boffs[tc] = (64 * wx + 16 * tc + m) * BK + swz;

    float best[16]; int bidx[16];
    #pragma unroll
    for (int s = 0; s < 16; ++s) { best[s] = FLT_MAX; bidx[s] = 0; }

    // prologue: A(0)->buf0, A(1)->buf1, B(0); full drain (one-time); then loop
    ASTAGE(0, 0);
    ASTAGE(1, 1);
    BSTAGE(0, 0);
    asm volatile("s_waitcnt vmcnt(0)" ::: "memory");
    __builtin_amdgcn_s_barrier();
    __builtin_amdgcn_sched_barrier(0);

    for (int chunk = 0; chunk < NCHUNK; ++chunk) {
        f32x4 acc[4][4];
        #pragma unroll
        for (int tr = 0; tr < 4; ++tr)
            #pragma unroll
            for (int tc = 0; tc < 4; ++tc) acc[tr][tc] = (f32x4){0.f, 0.f, 0.f, 0.f};

        #pragma unroll
        for (int sl = 0; sl < NSLICE; ++sl) {
            const int abuf = sl & 1;                 // j = chunk*8+sl; j&1 == sl&1
            const _Float16* Ahr = AhS + abuf * 4096;
            const _Float16* Alr = AlS + abuf * 4096;

            // staggered frag reads: peak frag liveness ~48 regs instead of 64
            half8 aH[4], aL[4], bH[4], bL[4];
            #pragma unroll
            for (int tr = 0; tr < 4; ++tr) aH[tr] = *(const half8*)&Ahr[aoffs[tr]];
            #pragma unroll
            for (int tc = 0; tc < 4; ++tc) bH[tc] = *(const half8*)&BhS[boffs[tc]];
            SWEEP(aH, bH);
            #pragma unroll
            for (int tc = 0; tc < 4; ++tc) bL[tc] = *(const half8*)&BlS[boffs[tc]];
            SWEEP(aH, bL);
            #pragma unroll
            for (int tr = 0; tr < 4; ++tr) aL[tr] = *(const half8*)&Alr[aoffs[tr]];
            SWEEP(aL, bH);

            const bool last = (chunk == NCHUNK - 1) && (sl == NSLICE - 1);
            if (!last) {
                const int j  = chunk * NSLICE + sl;
                const int jb = j + 1;                    // B slice to stage (single buf)
                const int ja = j + 2;                    // A slice to stage (buf ja&1 == abuf)
                const bool stgA = (ja < NITER);
                // rendezvous: all waves done reading A[j](abuf) and B[j]
                asm volatile("s_waitcnt lgkmcnt(0)" ::: "memory");
                __builtin_amdgcn_s_barrier();
                __builtin_amdgcn_sched_barrier(0);
                BSTAGE(jb >> 3, jb & 7);
                if (stgA) {
                    ASTAGE(ja & 7, abuf);
                    // retire A(j+1)+B(j+1) (and anything older); keep A(j+2) in flight
                    asm volatile("s_waitcnt vmcnt(4)" ::: "memory");
                } else {
                    asm volatile("s_waitcnt vmcnt(0)" ::: "memory");
                }
                __builtin_amdgcn_s_barrier();
                __builtin_amdgcn_sched_barrier(0);
            }

            if (sl == NSLICE - 1) {
                // chunk epilogue: dist + running argmin (cols ascend); xr/cs loaded here
                const int c0 = chunk * BN;
                float xr[16];
                #pragma unroll
                for (int s = 0; s < 16; ++s)
                    xr[s] = xsqg[n0 + 64 * wy + 16 * (s >> 2) + 4 * q + (s & 3)];
                float cs[4];
                #pragma unroll
                for (int tc = 0; tc < 4; ++tc) cs[tc] = csq[c0 + 64 * wx + 16 * tc + m];
                #pragma unroll
                for (int tc = 0; tc < 4; ++tc) {
                    int c = c0 + 64 * wx + 16 * tc + m;
                    #pragma unroll
                    for (int tr = 0; tr < 4; ++tr) {
                        #pragma unroll
                        for (int e = 0; e < 4; ++e) {
                            float dot = acc[tr][tc][e] * 0.015625f;     // exact /64
                            float d = fmaf(-2.f, dot, xr[tr * 4 + e]) + cs[tc];
                            int s = tr * 4 + e;
                            if (d < best[s]) { best[s] = d; bidx[s] = c; }
                        }
                    }
                }
            }
        }
    }

    // reduce across the 16 lanes of each quad-group (same physical rows)
    #pragma unroll
    for (int s = 0; s < 16; ++s) {
        float v = best[s]; int idx = bidx[s];
        #pragma unroll
        for (int off = 1; off < 16; off <<= 1) {
            float v2 = __shfl_xor(v, off);
            int   i2 = __shfl_xor(idx, off);
            if (v2 < v || (v2 == v && i2 < idx)) { v = v2; idx = i2; }
        }
        best[s] = v; bidx[s] = idx;
    }
    __syncthreads();                      // staging LDS free now
    float* rb = (float*)SMEM;             // [row][wx] candidates (1KB)
    int*   ri = (int*)(SMEM + 16384);     // (1KB)
    {
        int s = m;                        // lane writes slot == lane&15 (bijective over rows)
        int row_local = 64 * wy + 16 * (s >> 2) + 4 * q + (s & 3);
        rb[row_local * 2 + wx] = best[s];
        ri[row_local * 2 + wx] = bidx[s];
    }
    __syncthreads();
    int* widx = (int*)(SMEM + 32768);
    if (t < BM) {
        float d0 = rb[t * 2], d1 = rb[t * 2 + 1];
        int   i0 = ri[t * 2], i1 = ri[t * 2 + 1];
        int w = (d1 < d0 || (d1 == d0 && i1 < i0)) ? i1 : i0;
        widx[t] = w;
        out_idx[n0 + t] = (float)w;
    }
    __syncthreads();
    // gather winners, coalesced float4 (overwrites this block's packed-x scratch — all A reads done)
    const int l4 = t & 63, rg = t >> 6;
    #pragma unroll 4
    for (int i = 0; i < 32; ++i) {
        int r = rg + 4 * i;
        *(float4*)&out_q[(size_t)(n0 + r) * DIM + l4 * 4] =
            *(const float4*)&cb[(size_t)widx[r] * DIM + l4 * 4];
    }
#undef ASTAGE
#undef BSTAGE
#undef SWEEP
}

extern "C" void kernel_launch(void* const* d_in, const int* in_sizes, int n_in,
                              void* d_out, int out_size, void* d_ws, size_t ws_size,
                              hipStream_t stream) {
    const float* x  = (const float*)d_in[0];
    const float* cb = (const float*)d_in[1];
    float* out_q   = (float*)d_out;
    float* out_idx = (float*)d_out + (size_t)N_ROWS * DIM;

    float*    csq  = (float*)((char*)d_ws + WS_CSQ);
    float*    xsqg = (float*)((char*)d_ws + WS_XSQ);
    _Float16* ch   = (_Float16*)((char*)d_ws + WS_CH);
    _Float16* cl   = (_Float16*)((char*)d_ws + WS_CL);

    prep_codes<<<KCODES / 32, 256, 0, stream>>>(cb, csq, ch, cl);
    vq_mfma<<<N_ROWS / BM, 256, 0, stream>>>(x, cb, csq, ch, cl, xsqg, out_q, out_idx);
}